// Round 8
// baseline (330.244 us; speedup 1.0000x reference)
//
#include <hip/hip_runtime.h>
#include <hip/hip_bf16.h>
#include <stdint.h>

typedef __bf16 bf16_t;
typedef bf16_t bf16x8 __attribute__((ext_vector_type(8)));
typedef bf16_t bf16x4 __attribute__((ext_vector_type(4)));
typedef float f32x4 __attribute__((ext_vector_type(4)));

#define BATCH 16
#define HH    56
#define DIMK  384
#define M_TOT (BATCH*HH*HH)   // 50176
#define SCALE 0.17677669529663687f

__device__ __forceinline__ void async_load16(const bf16_t* g, const bf16_t* l) {
  __builtin_amdgcn_global_load_lds((const __attribute__((address_space(1))) void*)g,
                                   (__attribute__((address_space(3))) void*)l,
                                   16, 0, 0);
}

// DPP rotate within 16-lane row (VALU pipe — keeps softmax off the LDS pipe)
template<int CTRL>
__device__ __forceinline__ float dpp_ror(float x) {
  return __int_as_float(__builtin_amdgcn_mov_dpp(__float_as_int(x), CTRL, 0xf, 0xf, false));
}
__device__ __forceinline__ float rowmax16(float v) {
  v = fmaxf(v, dpp_ror<0x121>(v));  // row_ror:1
  v = fmaxf(v, dpp_ror<0x122>(v));  // row_ror:2
  v = fmaxf(v, dpp_ror<0x124>(v));  // row_ror:4
  v = fmaxf(v, dpp_ror<0x128>(v));  // row_ror:8
  return v;
}
__device__ __forceinline__ float rowsum16(float v) {
  v += dpp_ror<0x121>(v);
  v += dpp_ror<0x122>(v);
  v += dpp_ror<0x124>(v);
  v += dpp_ror<0x128>(v);
  return v;
}

// ---------------------------------------------------------------------------
__global__ void k_zero(float* __restrict__ p, int n) {
  int i = blockIdx.x * 256 + threadIdx.x;
  if (i < n) p[i] = 0.f;
}

// transpose w_qkv [384][1152] fp32 -> wT [1152][384] bf16  (round-5 proven)
__global__ void k_transpose(const float* __restrict__ w, bf16_t* __restrict__ wT) {
  int idx = blockIdx.x * 256 + threadIdx.x;
  if (idx >= 1152 * 384) return;
  int n = idx / 384, k = idx - n * 384;
  wT[idx] = (bf16_t)w[k * 1152 + n];
}

// wcombT[n][k] = sum_j w_out[k][j] * w_post[j][n]; bcomb[n] = b_out@w_post + b_post
__global__ void k_comb(const float* __restrict__ w_out, const float* __restrict__ b_out,
                       const float* __restrict__ w_post, const float* __restrict__ b_post,
                       bf16_t* __restrict__ wcombT, float* __restrict__ bcomb) {
  __shared__ float col[384];
  const int n = blockIdx.x, t = threadIdx.x;
  for (int j = t; j < 384; j += 256) col[j] = w_post[j * 384 + n];
  __syncthreads();
  for (int k = t; k < 384; k += 256) {
    float acc = 0.f;
    for (int j = 0; j < 384; ++j) acc += w_out[k * 384 + j] * col[j];
    wcombT[n * 384 + k] = (bf16_t)acc;
  }
  if (t == 0) {
    float acc = b_post[n];
    for (int j = 0; j < 384; ++j) acc += b_out[j] * col[j];
    bcomb[n] = acc;
  }
}

// bias/mask init table in MFMA C-layout, pre-divided by SCALE.
__global__ void k_bias(const float* __restrict__ pos, float* __restrict__ biasC) {
  int idx = blockIdx.x * 256 + threadIdx.x;
  if (idx >= 4 * 16 * 64 * 4) return;
  int reg = idx & 3, lane = (idx >> 2) & 63, tile = (idx >> 8) & 15, cls = idx >> 12;
  int mt = tile >> 2, nt = tile & 3, lc = lane & 15, quad = lane >> 4;
  int m = mt * 16 + quad * 4 + reg, n = nt * 16 + lc;
  float v = -1e32f;
  if (m < 49 && n < 49) {
    int ty = m / 7, tx = m % 7, jy = n / 7, jx = n % 7;
    bool dead = ((cls & 1) && ((m >= 28) != (n >= 28))) ||
                ((cls & 2) && ((tx >= 4) != (jx >= 4)));
    v = dead ? -1e32f : pos[(jy - ty + 6) * 13 + (jx - tx + 6)] * (1.0f / SCALE);
  }
  biasC[idx] = v;
}

// ---------------------------------------------------------------------------
// k_gemm_qkv: qkv[M x 1152] = roll(-3,-3)(x fp32)[M x 384] @ wT^T, FUSED:
// the A-operand is reg-staged straight from x (f32x4 pairs -> cvt -> ds_write,
// roll folded into the per-thread source-row address) — this DELETES the
// standalone convroll kernel (~95 us prep, round-7 profile) and its 116 MB
// round trip. B stays global_load_lds. LDS layout + XOR chunk swizzle and the
// BK=64 depth-1 structure are unchanged from the proven round-5 kernel.
// T14 ordering: A loads issued right after the barrier, cvt+ds_write sunk
// below the MFMA cluster so load latency hides under compute.
__global__ __launch_bounds__(256)
void k_gemm_qkv(const float* __restrict__ X, const bf16_t* __restrict__ B,
                bf16_t* __restrict__ C) {
  __shared__ __align__(16) bf16_t As[2][128 * 64];
  __shared__ __align__(16) bf16_t Bs[2][128 * 64];
  const int tid  = threadIdx.x;
  const int wave = tid >> 6;
  const int lane = tid & 63;
  const int wr = wave >> 1, wc = wave & 1;

  const int gx   = gridDim.x;                     // 9
  const int nwg  = gx * gridDim.y;                // 3528 (div by 8)
  const int flat = blockIdx.y * gx + blockIdx.x;
  const int qch  = nwg >> 3;
  const int nf   = (flat & 7) * qch + (flat >> 3);
  const int bx   = nf % gx;
  const int by   = nf / gx;
  const int row0 = by * 128;
  const int col0 = bx * 128;

  // staging map: slot (r, kc) holds GLOBAL chunk (r, gk = kc ^ (r&7)).
  // A source: x row srow(row0+r) (roll -3,-3 folded), fp32, col gk*8.
  const float*  axp[4];
  const bf16_t* bptr[4];
  int dst[4];
#pragma unroll
  for (int c = 0; c < 4; ++c) {
    int linear = c * 256 + tid;
    int r  = linear >> 3;
    int kc = linear & 7;
    int gk = kc ^ (r & 7);
    dst[c] = linear * 8;
    int grow = row0 + r;
    int bb = grow / 3136, rem = grow - bb * 3136;
    int i = rem / 56, j = rem - i * 56;
    int si = i + 3; if (si >= 56) si -= 56;
    int sj = j + 3; if (sj >= 56) sj -= 56;
    axp[c]  = X + (size_t)(bb * 3136 + si * 56 + sj) * 384 + gk * 8;
    bptr[c] = B + (size_t)(col0 + r) * 384 + gk * 8;
  }

  f32x4 acc[4][4] = {};
  const int lr = lane >> 4;
  const int lc = lane & 15;
  unsigned aoff[4][2], boff[4][2];
#pragma unroll
  for (int mi = 0; mi < 4; ++mi)
#pragma unroll
    for (int kh = 0; kh < 2; ++kh) {
      int arow = wr * 64 + mi * 16 + lc;
      int brow = wc * 64 + mi * 16 + lc;
      int sc   = (kh * 4 + lr) ^ (lc & 7);
      aoff[mi][kh] = (unsigned)(arow * 64 + sc * 8);
      boff[mi][kh] = (unsigned)(brow * 64 + sc * 8);
    }

  const int kiters = 6;   // K = 384, BK = 64

  // prologue: stage K-step 0 into buffer 0 (A via regs, B via gload_lds)
  {
    f32x4 a0[4], a1[4];
#pragma unroll
    for (int c = 0; c < 4; ++c) {
      a0[c] = *(const f32x4*)(axp[c]);
      a1[c] = *(const f32x4*)(axp[c] + 4);
    }
#pragma unroll
    for (int c = 0; c < 4; ++c) async_load16(bptr[c], Bs[0] + dst[c]);
#pragma unroll
    for (int c = 0; c < 4; ++c) {
      bf16x8 o;
#pragma unroll
      for (int u = 0; u < 4; ++u) { o[u] = (bf16_t)a0[c][u]; o[4 + u] = (bf16_t)a1[c][u]; }
      *(bf16x8*)(As[0] + dst[c]) = o;
    }
  }

  for (int kt = 0; kt < kiters; ++kt) {
    const int cur = kt & 1;
    __syncthreads();   // drains prev stage (B vmcnt + A lgkm) before reuse

    f32x4 a0[4], a1[4];
    const bool pf = (kt + 1 < kiters);
    if (pf) {
      const int koff = (kt + 1) * 64;
#pragma unroll
      for (int c = 0; c < 4; ++c) {        // issue A loads EARLY (T14)
        a0[c] = *(const f32x4*)(axp[c] + koff);
        a1[c] = *(const f32x4*)(axp[c] + koff + 4);
      }
#pragma unroll
      for (int c = 0; c < 4; ++c) async_load16(bptr[c] + koff, Bs[cur ^ 1] + dst[c]);
    }

    bf16x8 af[4][2], bfr[4][2];
#pragma unroll
    for (int mi = 0; mi < 4; ++mi)
#pragma unroll
      for (int kh = 0; kh < 2; ++kh) {
        af[mi][kh]  = *(const bf16x8*)(As[cur] + aoff[mi][kh]);
        bfr[mi][kh] = *(const bf16x8*)(Bs[cur] + boff[mi][kh]);
      }
#pragma unroll
    for (int kh = 0; kh < 2; ++kh)
#pragma unroll
      for (int mi = 0; mi < 4; ++mi)
#pragma unroll
        for (int ni = 0; ni < 4; ++ni)
          acc[mi][ni] = __builtin_amdgcn_mfma_f32_16x16x32_bf16(af[mi][kh], bfr[ni][kh], acc[mi][ni], 0, 0, 0);

    if (pf) {                              // write LATE: cvt+ds_write sink below MFMAs
#pragma unroll
      for (int c = 0; c < 4; ++c) {
        bf16x8 o;
#pragma unroll
        for (int u = 0; u < 4; ++u) { o[u] = (bf16_t)a0[c][u]; o[4 + u] = (bf16_t)a1[c][u]; }
        *(bf16x8*)(As[cur ^ 1] + dst[c]) = o;
      }
    }
  }

  // Epilogue: C/D layout col=lane&15, row=quad*4+reg (verified m89/m91)
#pragma unroll
  for (int mi = 0; mi < 4; ++mi)
#pragma unroll
    for (int rr = 0; rr < 4; ++rr) {
      int grow = row0 + wr * 64 + mi * 16 + lr * 4 + rr;
#pragma unroll
      for (int ni = 0; ni < 4; ++ni) {
        int gcol = col0 + wc * 64 + ni * 16 + lc;
        C[(size_t)grow * 1152 + gcol] = (bf16_t)acc[mi][ni][rr];
      }
    }
}

// ---------------------------------------------------------------------------
// k_gemm_out: out = roll^{-1}(attn @ wcomb + bcomb). Round-5 proven body:
// BK=64 depth-1 dbuf, gload_lds both operands, XOR chunk swizzle, T1 swizzle,
// fp32 C write with fused roll(+3,+3) + bias.
__global__ __launch_bounds__(256)
void k_gemm_out(const bf16_t* __restrict__ A, const bf16_t* __restrict__ B,
                float* __restrict__ Cv, const float* __restrict__ bias,
                int Ndim, int Kdim, int lda) {
  __shared__ __align__(16) bf16_t As[2][128 * 64];
  __shared__ __align__(16) bf16_t Bs[2][128 * 64];
  const int tid  = threadIdx.x;
  const int wave = tid >> 6;
  const int lane = tid & 63;
  const int wr = wave >> 1, wc = wave & 1;

  const int gx   = gridDim.x;
  const int nwg  = gx * gridDim.y;
  const int flat = blockIdx.y * gx + blockIdx.x;
  const int qch  = nwg >> 3;
  const int nf   = (flat & 7) * qch + (flat >> 3);
  const int bx   = nf % gx;
  const int by   = nf / gx;
  const int row0 = by * 128;
  const int col0 = bx * 128;

  const bf16_t* aptr[4];
  const bf16_t* bptr[4];
  int dst[4];
#pragma unroll
  for (int c = 0; c < 4; ++c) {
    int linear = c * 256 + tid;
    int r  = linear >> 3;
    int kc = linear & 7;
    int gk = kc ^ (r & 7);
    dst[c] = linear * 8;
    aptr[c] = A + (size_t)(row0 + r) * lda + gk * 8;
    bptr[c] = B + (size_t)(col0 + r) * Kdim + gk * 8;
  }

  f32x4 acc[4][4] = {};
  const int lr = lane >> 4;
  const int lc = lane & 15;
  unsigned aoff[4][2], boff[4][2];
#pragma unroll
  for (int mi = 0; mi < 4; ++mi)
#pragma unroll
    for (int kh = 0; kh < 2; ++kh) {
      int arow = wr * 64 + mi * 16 + lc;
      int brow = wc * 64 + mi * 16 + lc;
      int sc   = (kh * 4 + lr) ^ (lc & 7);
      aoff[mi][kh] = (unsigned)(arow * 64 + sc * 8);
      boff[mi][kh] = (unsigned)(brow * 64 + sc * 8);
    }

  const int kiters = Kdim >> 6;

#pragma unroll
  for (int c = 0; c < 4; ++c) {
    async_load16(aptr[c], As[0] + dst[c]);
    async_load16(bptr[c], Bs[0] + dst[c]);
  }

  for (int kt = 0; kt < kiters; ++kt) {
    const int cur = kt & 1;
    __syncthreads();
    if (kt + 1 < kiters) {
      const int koff = (kt + 1) * 64;
#pragma unroll
      for (int c = 0; c < 4; ++c) {
        async_load16(aptr[c] + koff, As[cur ^ 1] + dst[c]);
        async_load16(bptr[c] + koff, Bs[cur ^ 1] + dst[c]);
      }
    }
    bf16x8 af[4][2], bfr[4][2];
#pragma unroll
    for (int mi = 0; mi < 4; ++mi)
#pragma unroll
      for (int kh = 0; kh < 2; ++kh) {
        af[mi][kh]  = *(const bf16x8*)(As[cur] + aoff[mi][kh]);
        bfr[mi][kh] = *(const bf16x8*)(Bs[cur] + boff[mi][kh]);
      }
#pragma unroll
    for (int kh = 0; kh < 2; ++kh)
#pragma unroll
      for (int mi = 0; mi < 4; ++mi)
#pragma unroll
        for (int ni = 0; ni < 4; ++ni)
          acc[mi][ni] = __builtin_amdgcn_mfma_f32_16x16x32_bf16(af[mi][kh], bfr[ni][kh], acc[mi][ni], 0, 0, 0);
  }

#pragma unroll
  for (int mi = 0; mi < 4; ++mi)
#pragma unroll
    for (int rr = 0; rr < 4; ++rr) {
      int grow = row0 + wr * 64 + mi * 16 + lr * 4 + rr;
      int bb  = grow / 3136;
      int rem = grow - bb * 3136;
      int i = rem / 56;
      int j = rem - i * 56;
      int si = i + 3; if (si >= 56) si -= 56;
      int sj = j + 3; if (sj >= 56) sj -= 56;
      size_t orow = (size_t)(bb * 3136 + si * 56 + sj);   // fused roll(+3,+3)
#pragma unroll
      for (int ni = 0; ni < 4; ++ni) {
        int gcol = col0 + wc * 64 + ni * 16 + lc;
        Cv[orow * (size_t)Ndim + gcol] = acc[mi][ni][rr] + bias[gcol];
      }
    }
}

// ---------------------------------------------------------------------------
// MFMA attention (round-5 proven, with T5 setprio): one wave per
// (b, head, window); 4 waves/block; output in place into the q slot.
__global__ __launch_bounds__(256)
void k_attn(const float* __restrict__ biasC, bf16_t* __restrict__ qkv) {
  __shared__ __align__(16) bf16_t Ps[4 * 64 * 72];   // 36864 B
  const int tid = threadIdx.x, wid = tid >> 6, lane = tid & 63;
  const int p = blockIdx.x * 4 + wid;                 // 12288 problems
  const int b = p / 768, rem = p - b * 768;
  const int head = rem >> 6, w = rem & 63;
  const int wy = w >> 3, wx = w & 7;
  const int cls = ((wy == 7) ? 1 : 0) | ((wx == 7) ? 2 : 0);
  const int lc = lane & 15, quad = lane >> 4;
  const size_t wbase = ((size_t)b * 3136 + (size_t)wy * 7 * 56 + (size_t)wx * 7) * 1152
                       + head * 32;

  auto rowoff = [&](int m) -> size_t {
    int ty = m / 7, tx = m - ty * 7;
    return wbase + (size_t)(ty * 56 + tx) * 1152;
  };

  bf16x8 qf[4], kf[4];
#pragma unroll
  for (int t = 0; t < 4; ++t) {
    int m = t * 16 + lc; if (m > 48) m = 48;
    const bf16_t* r = qkv + rowoff(m);
    qf[t] = *(const bf16x8*)(r + quad * 8);
    kf[t] = *(const bf16x8*)(r + 384 + quad * 8);
  }

  bf16x8 vf[2][2];
#pragma unroll
  for (int kc = 0; kc < 2; ++kc)
#pragma unroll
    for (int u = 0; u < 8; ++u) {
      int n = kc * 32 + quad * 8 + u; if (n > 48) n = 48;
      const bf16_t* r = qkv + rowoff(n) + 768 + lc;
      vf[kc][0][u] = r[0];
      vf[kc][1][u] = r[16];
    }

  f32x4 acc[4][4];
  const float* bp = biasC + cls * 4096 + lane * 4;
#pragma unroll
  for (int mt = 0; mt < 4; ++mt)
#pragma unroll
    for (int nt = 0; nt < 4; ++nt)
      acc[mt][nt] = *(const f32x4*)(bp + (mt * 4 + nt) * 256);
  __builtin_amdgcn_s_setprio(1);
#pragma unroll
  for (int mt = 0; mt < 4; ++mt)
#pragma unroll
    for (int nt = 0; nt < 4; ++nt)
      acc[mt][nt] = __builtin_amdgcn_mfma_f32_16x16x32_bf16(qf[mt], kf[nt], acc[mt][nt], 0, 0, 0);
  __builtin_amdgcn_s_setprio(0);

  float l[4][4];
#pragma unroll
  for (int mt = 0; mt < 4; ++mt)
#pragma unroll
    for (int reg = 0; reg < 4; ++reg) {
      float mx = fmaxf(fmaxf(acc[mt][0][reg], acc[mt][1][reg]),
                       fmaxf(acc[mt][2][reg], acc[mt][3][reg]));
      mx = rowmax16(mx);
      float s = 0.f;
#pragma unroll
      for (int nt = 0; nt < 4; ++nt) {
        float pe = __expf((acc[mt][nt][reg] - mx) * SCALE);
        acc[mt][nt][reg] = pe;
        s += pe;
      }
      l[mt][reg] = rowsum16(s);
    }

  bf16_t* P = Ps + wid * (64 * 72);
#pragma unroll
  for (int mt = 0; mt < 4; ++mt)
#pragma unroll
    for (int nt = 0; nt < 4; ++nt)
#pragma unroll
      for (int reg = 0; reg < 4; ++reg)
        P[(mt * 16 + quad * 4 + reg) * 72 + nt * 16 + lc] = (bf16_t)acc[mt][nt][reg];

  f32x4 oacc[4][2] = {};
#pragma unroll
  for (int mt = 0; mt < 4; ++mt) {
    bf16x8 pf0 = *(const bf16x8*)(P + (mt * 16 + lc) * 72 + quad * 8);
    bf16x8 pf1 = *(const bf16x8*)(P + (mt * 16 + lc) * 72 + 32 + quad * 8);
    __builtin_amdgcn_s_setprio(1);
#pragma unroll
    for (int dt = 0; dt < 2; ++dt) {
      oacc[mt][dt] = __builtin_amdgcn_mfma_f32_16x16x32_bf16(pf0, vf[0][dt], oacc[mt][dt], 0, 0, 0);
      oacc[mt][dt] = __builtin_amdgcn_mfma_f32_16x16x32_bf16(pf1, vf[1][dt], oacc[mt][dt], 0, 0, 0);
    }
    __builtin_amdgcn_s_setprio(0);
  }

#pragma unroll
  for (int mt = 0; mt < 4; ++mt)
#pragma unroll
    for (int reg = 0; reg < 4; ++reg) {
      int m = mt * 16 + quad * 4 + reg;
      if (m < 49) {
        float rl = __builtin_amdgcn_rcpf(l[mt][reg]);
        bf16_t* r = qkv + rowoff(m);
        r[lc]      = (bf16_t)(oacc[mt][0][reg] * rl);
        r[16 + lc] = (bf16_t)(oacc[mt][1][reg] * rl);
      }
    }
}

// ---------------------------------------------------------------------------
extern "C" void kernel_launch(void* const* d_in, const int* in_sizes, int n_in,
                              void* d_out, int out_size, void* d_ws, size_t ws_size,
                              hipStream_t stream) {
  const float* x      = (const float*)d_in[0];
  const float* w_qkv  = (const float*)d_in[1];
  const float* pos    = (const float*)d_in[2];
  const float* w_out  = (const float*)d_in[3];
  const float* b_out  = (const float*)d_in[4];
  const float* w_post = (const float*)d_in[5];
  const float* b_post = (const float*)d_in[6];
  float* out = (float*)d_out;

  const size_t SZ_QKV  = (size_t)M_TOT * 1152 * 2;   // 115.6 MB
  const size_t SZ_WT   = (size_t)1152 * 384 * 2;
  const size_t SZ_WC   = (size_t)384 * 384 * 2;
  const size_t SZ_BC   = 384 * 4;
  const size_t SZ_BIAS = (size_t)4 * 16 * 64 * 4 * 4;  // 64 KB
  const size_t NEEDED  = SZ_QKV + SZ_WT + SZ_WC + SZ_BC + SZ_BIAS;

  if (ws_size < NEEDED) {
    k_zero<<<(out_size + 255) / 256, 256, 0, stream>>>(out, out_size);
    return;
  }

  char* ws = (char*)d_ws;
  bf16_t* qkv   = (bf16_t*)ws;
  bf16_t* wT    = (bf16_t*)(ws + SZ_QKV);
  bf16_t* wcT   = (bf16_t*)(ws + SZ_QKV + SZ_WT);
  float*  bc    = (float*)(ws + SZ_QKV + SZ_WT + SZ_WC);
  float*  biasC = (float*)(ws + SZ_QKV + SZ_WT + SZ_WC + SZ_BC);

  k_transpose<<<1728, 256, 0, stream>>>(w_qkv, wT);
  k_comb<<<384, 256, 0, stream>>>(w_out, b_out, w_post, b_post, wcT, bc);
  k_bias<<<64, 256, 0, stream>>>(pos, biasC);
  // qkv = roll(-3,-3)(x) @ w_qkv^T-laid-out — convroll FUSED into A-staging
  k_gemm_qkv<<<dim3(9, 392), 256, 0, stream>>>(x, wT, qkv);
  // attention in place (q slot)
  k_attn<<<3072, 256, 0, stream>>>(biasC, qkv);
  // out = roll^{-1}( attn @ wcomb + bcomb )   [50176 x 384] fp32
  k_gemm_out<<<dim3(3, 392), 256, 0, stream>>>(qkv, wcT, out, bc, 384, DIMK, 1152);
}

// Round 9
// 296.457 us; speedup vs baseline: 1.1140x; 1.1140x over previous
//
#include <hip/hip_runtime.h>
#include <hip/hip_bf16.h>
#include <stdint.h>

typedef __bf16 bf16_t;
typedef bf16_t bf16x8 __attribute__((ext_vector_type(8)));
typedef bf16_t bf16x4 __attribute__((ext_vector_type(4)));
typedef float f32x4 __attribute__((ext_vector_type(4)));

#define BATCH 16
#define HH    56
#define DIMK  384
#define M_TOT (BATCH*HH*HH)   // 50176
#define SCALE 0.17677669529663687f

__device__ __forceinline__ void async_load16(const bf16_t* g, const bf16_t* l) {
  __builtin_amdgcn_global_load_lds((const __attribute__((address_space(1))) void*)g,
                                   (__attribute__((address_space(3))) void*)l,
                                   16, 0, 0);
}

// DPP rotate within 16-lane row (VALU pipe — keeps softmax off the LDS pipe)
template<int CTRL>
__device__ __forceinline__ float dpp_ror(float x) {
  return __int_as_float(__builtin_amdgcn_mov_dpp(__float_as_int(x), CTRL, 0xf, 0xf, false));
}
__device__ __forceinline__ float rowmax16(float v) {
  v = fmaxf(v, dpp_ror<0x121>(v));  // row_ror:1
  v = fmaxf(v, dpp_ror<0x122>(v));  // row_ror:2
  v = fmaxf(v, dpp_ror<0x124>(v));  // row_ror:4
  v = fmaxf(v, dpp_ror<0x128>(v));  // row_ror:8
  return v;
}
__device__ __forceinline__ float rowsum16(float v) {
  v += dpp_ror<0x121>(v);
  v += dpp_ror<0x122>(v);
  v += dpp_ror<0x124>(v);
  v += dpp_ror<0x128>(v);
  return v;
}

// ---------------------------------------------------------------------------
__global__ void k_zero(float* __restrict__ p, int n) {
  int i = blockIdx.x * 256 + threadIdx.x;
  if (i < n) p[i] = 0.f;
}

// transpose w_qkv [384][1152] fp32 -> wT [1152][384] bf16.
// 64x64 LDS tile (verified correct inside round-7 k_prep): coalesced f32x4
// reads, coalesced bf16x4 writes. Replaces the stride-4.6KB uncoalesced
// round-5 version (~35 us inferred).
__global__ __launch_bounds__(256)
void k_transpose(const float* __restrict__ w, bf16_t* __restrict__ wT) {
  __shared__ float sbuf[64 * 65];
  const int t = threadIdx.x;
  int blk = blockIdx.x;                    // 108 = 18 x 6
  int tn = blk % 18, tk = blk / 18;
  int k0 = tk * 64, n0 = tn * 64;
#pragma unroll
  for (int s = 0; s < 4; ++s) {
    int r = (t >> 4) + s * 16;
    int c = (t & 15) * 4;
    f32x4 v = *(const f32x4*)(w + (size_t)(k0 + r) * 1152 + n0 + c);
#pragma unroll
    for (int u = 0; u < 4; ++u) sbuf[r * 65 + c + u] = v[u];
  }
  __syncthreads();
#pragma unroll
  for (int s = 0; s < 4; ++s) {
    int rn = (t >> 4) + s * 16;
    int ck = (t & 15) * 4;
    bf16x4 o;
#pragma unroll
    for (int u = 0; u < 4; ++u) o[u] = (bf16_t)sbuf[(ck + u) * 65 + rn];
    *(bf16x4*)(wT + (size_t)(n0 + rn) * 384 + k0 + ck) = o;
  }
}

// wcombT[n][k] = sum_j w_out[k][j] * w_post[j][n] — tiled SGEMM, 36 blocks of
// 64x64 C-tiles, both operands LDS-staged (stride 68: 16B-aligned f32x4 rows,
// broadcast column reads). Replaces the thread-serial round-5 comb (~45 us
// inferred). bcomb folded into the blockIdx.x==0 blocks.
__global__ __launch_bounds__(256)
void k_comb(const float* __restrict__ w_out, const float* __restrict__ b_out,
            const float* __restrict__ w_post, const float* __restrict__ b_post,
            bf16_t* __restrict__ wcombT, float* __restrict__ bcomb) {
  __shared__ float Wo[64][68];   // [k_local][j_local]
  __shared__ float Wp[64][68];   // [j_local][n_local]
  const int t  = threadIdx.x;
  const int k0 = blockIdx.x * 64, n0 = blockIdx.y * 64;
  const int tx = t & 15, ty = t >> 4;       // tx -> n, ty -> k
  float acc[4][4] = {};                      // [kb][na]

  for (int j0 = 0; j0 < 384; j0 += 64) {
    __syncthreads();   // protect prior-iteration LDS reads
#pragma unroll
    for (int s = 0; s < 4; ++s) {
      int lin = s * 256 + t;
      int r = lin >> 4, c4 = (lin & 15) * 4;
      f32x4 va = *(const f32x4*)(w_out  + (size_t)(k0 + r) * 384 + j0 + c4);
      f32x4 vb = *(const f32x4*)(w_post + (size_t)(j0 + r) * 384 + n0 + c4);
      *(f32x4*)&Wo[r][c4] = va;
      *(f32x4*)&Wp[r][c4] = vb;
    }
    __syncthreads();
    for (int j = 0; j < 64; ++j) {
      f32x4 a = *(const f32x4*)&Wp[j][tx * 4];     // contiguous, conflict-free
      float b0 = Wo[ty * 4 + 0][j];                // broadcast reads
      float b1 = Wo[ty * 4 + 1][j];
      float b2 = Wo[ty * 4 + 2][j];
      float b3 = Wo[ty * 4 + 3][j];
#pragma unroll
      for (int na = 0; na < 4; ++na) {
        acc[0][na] += b0 * a[na];
        acc[1][na] += b1 * a[na];
        acc[2][na] += b2 * a[na];
        acc[3][na] += b3 * a[na];
      }
    }
  }
  // write: wcombT[n0+tx*4+na][k0+ty*4+kb] (contiguous bf16x4 in k)
#pragma unroll
  for (int na = 0; na < 4; ++na) {
    int n = n0 + tx * 4 + na;
    bf16x4 o;
#pragma unroll
    for (int kb = 0; kb < 4; ++kb) o[kb] = (bf16_t)acc[kb][na];
    *(bf16x4*)(wcombT + (size_t)n * 384 + k0 + ty * 4) = o;
  }
  // bcomb[n] = b_out @ w_post[:,n] + b_post[n] — done by the k0==0 blocks
  if (blockIdx.x == 0) {
    __syncthreads();
    float* part = &Wo[0][0];                 // reuse LDS: 4 x 64 partials
    int tj = t >> 6, nl = t & 63;
    float s = 0.f;
    for (int j = tj * 96; j < tj * 96 + 96; ++j)
      s += b_out[j] * w_post[(size_t)j * 384 + n0 + nl];
    part[tj * 64 + nl] = s;
    __syncthreads();
    if (t < 64)
      bcomb[n0 + t] = part[t] + part[64 + t] + part[128 + t] + part[192 + t]
                      + b_post[n0 + t];
  }
}

// bias/mask init table in MFMA C-layout, pre-divided by SCALE.
__global__ void k_bias(const float* __restrict__ pos, float* __restrict__ biasC) {
  int idx = blockIdx.x * 256 + threadIdx.x;
  if (idx >= 4 * 16 * 64 * 4) return;
  int reg = idx & 3, lane = (idx >> 2) & 63, tile = (idx >> 8) & 15, cls = idx >> 12;
  int mt = tile >> 2, nt = tile & 3, lc = lane & 15, quad = lane >> 4;
  int m = mt * 16 + quad * 4 + reg, n = nt * 16 + lc;
  float v = -1e32f;
  if (m < 49 && n < 49) {
    int ty = m / 7, tx = m % 7, jy = n / 7, jx = n % 7;
    bool dead = ((cls & 1) && ((m >= 28) != (n >= 28))) ||
                ((cls & 2) && ((tx >= 4) != (jx >= 4)));
    v = dead ? -1e32f : pos[(jy - ty + 6) * 13 + (jx - tx + 6)] * (1.0f / SCALE);
  }
  biasC[idx] = v;
}

// x fp32 -> bf16 with roll(-3,-3) fused (round-5 proven, ~25 us).
__global__ void k_convroll(const float* __restrict__ x, bf16_t* __restrict__ xb) {
  int idx = blockIdx.x * 256 + threadIdx.x;
  if (idx >= M_TOT * 48) return;
  int row = idx / 48, c = idx - row * 48;
  int bb = row / 3136, rem = row - bb * 3136, i = rem / 56, j = rem - i * 56;
  int si = i + 3; if (si >= 56) si -= 56;
  int sj = j + 3; if (sj >= 56) sj -= 56;
  const float* src = x + ((size_t)(bb * 3136 + si * 56 + sj)) * 384 + c * 8;
  f32x4 v0 = *(const f32x4*)src;
  f32x4 v1 = *(const f32x4*)(src + 4);
  bf16x8 o;
#pragma unroll
  for (int u = 0; u < 4; ++u) { o[u] = (bf16_t)v0[u]; o[4 + u] = (bf16_t)v1[u]; }
  *(bf16x8*)(xb + (size_t)row * 384 + c * 8) = o;
}

// ---------------------------------------------------------------------------
// GEMM body (round-5 proven: 68 us on qkv, 0 bank conflicts): 128x128 tile,
// BK=64, gload_lds both operands, depth-1 prefetch dbuf, XOR chunk swizzle
// (T2 via m173), XCD-chunk bijective swizzle (T1). MODE 1: fp32 C +
// roll(+3,+3) + bias.
template<int MODE>
__device__ __forceinline__
void gemm_body(const bf16_t* __restrict__ A, const bf16_t* __restrict__ B,
               void* __restrict__ Cv, const float* __restrict__ bias,
               int Ndim, int Kdim, int lda) {
  __shared__ __align__(16) bf16_t As[2][128 * 64];
  __shared__ __align__(16) bf16_t Bs[2][128 * 64];
  const int tid  = threadIdx.x;
  const int wave = tid >> 6;
  const int lane = tid & 63;
  const int wr = wave >> 1, wc = wave & 1;

  const int gx   = gridDim.x;
  const int nwg  = gx * gridDim.y;
  const int flat = blockIdx.y * gx + blockIdx.x;
  const int qch  = nwg >> 3;
  const int nf   = (flat & 7) * qch + (flat >> 3);
  const int bx   = nf % gx;
  const int by   = nf / gx;
  const int row0 = by * 128;
  const int col0 = bx * 128;

  const bf16_t* aptr[4];
  const bf16_t* bptr[4];
  int dst[4];
#pragma unroll
  for (int c = 0; c < 4; ++c) {
    int linear = c * 256 + tid;
    int r  = linear >> 3;
    int kc = linear & 7;
    int gk = kc ^ (r & 7);
    dst[c] = linear * 8;
    aptr[c] = A + (size_t)(row0 + r) * lda + gk * 8;
    bptr[c] = B + (size_t)(col0 + r) * Kdim + gk * 8;
  }

  f32x4 acc[4][4] = {};
  const int lr = lane >> 4;
  const int lc = lane & 15;
  unsigned aoff[4][2], boff[4][2];
#pragma unroll
  for (int mi = 0; mi < 4; ++mi)
#pragma unroll
    for (int kh = 0; kh < 2; ++kh) {
      int arow = wr * 64 + mi * 16 + lc;
      int brow = wc * 64 + mi * 16 + lc;
      int sc   = (kh * 4 + lr) ^ (lc & 7);
      aoff[mi][kh] = (unsigned)(arow * 64 + sc * 8);
      boff[mi][kh] = (unsigned)(brow * 64 + sc * 8);
    }

  const int kiters = Kdim >> 6;

#pragma unroll
  for (int c = 0; c < 4; ++c) {
    async_load16(aptr[c], As[0] + dst[c]);
    async_load16(bptr[c], Bs[0] + dst[c]);
  }

  for (int kt = 0; kt < kiters; ++kt) {
    const int cur = kt & 1;
    __syncthreads();
    if (kt + 1 < kiters) {
      const int koff = (kt + 1) * 64;
#pragma unroll
      for (int c = 0; c < 4; ++c) {
        async_load16(aptr[c] + koff, As[cur ^ 1] + dst[c]);
        async_load16(bptr[c] + koff, Bs[cur ^ 1] + dst[c]);
      }
    }
    bf16x8 af[4][2], bfr[4][2];
#pragma unroll
    for (int mi = 0; mi < 4; ++mi)
#pragma unroll
      for (int kh = 0; kh < 2; ++kh) {
        af[mi][kh]  = *(const bf16x8*)(As[cur] + aoff[mi][kh]);
        bfr[mi][kh] = *(const bf16x8*)(Bs[cur] + boff[mi][kh]);
      }
#pragma unroll
    for (int kh = 0; kh < 2; ++kh)
#pragma unroll
      for (int mi = 0; mi < 4; ++mi)
#pragma unroll
        for (int ni = 0; ni < 4; ++ni)
          acc[mi][ni] = __builtin_amdgcn_mfma_f32_16x16x32_bf16(af[mi][kh], bfr[ni][kh], acc[mi][ni], 0, 0, 0);
  }

#pragma unroll
  for (int mi = 0; mi < 4; ++mi)
#pragma unroll
    for (int rr = 0; rr < 4; ++rr) {
      int grow = row0 + wr * 64 + mi * 16 + lr * 4 + rr;
      size_t orow;
      if (MODE == 1) {
        int bb  = grow / 3136;
        int rem = grow - bb * 3136;
        int i = rem / 56;
        int j = rem - i * 56;
        int si = i + 3; if (si >= 56) si -= 56;
        int sj = j + 3; if (sj >= 56) sj -= 56;
        orow = (size_t)(bb * 3136 + si * 56 + sj);   // fused roll(+3,+3)
      } else {
        orow = (size_t)grow;
      }
#pragma unroll
      for (int ni = 0; ni < 4; ++ni) {
        int gcol = col0 + wc * 64 + ni * 16 + lc;
        float v = acc[mi][ni][rr];
        if (MODE == 1) {
          ((float*)Cv)[orow * (size_t)Ndim + gcol] = v + bias[gcol];
        } else {
          ((bf16_t*)Cv)[orow * (size_t)Ndim + gcol] = (bf16_t)v;
        }
      }
    }
}

__global__ __launch_bounds__(256)
void k_gemm_qkv(const bf16_t* __restrict__ A, const bf16_t* __restrict__ B,
                void* __restrict__ Cv, const float* __restrict__ bias,
                int Ndim, int Kdim, int lda) {
  gemm_body<0>(A, B, Cv, bias, Ndim, Kdim, lda);
}
__global__ __launch_bounds__(256)
void k_gemm_out(const bf16_t* __restrict__ A, const bf16_t* __restrict__ B,
                void* __restrict__ Cv, const float* __restrict__ bias,
                int Ndim, int Kdim, int lda) {
  gemm_body<1>(A, B, Cv, bias, Ndim, Kdim, lda);
}

// ---------------------------------------------------------------------------
// MFMA attention (round-5 proven, T5 setprio): one wave per (b, head, window);
// 4 waves/block; output in place into the q slot.
__global__ __launch_bounds__(256)
void k_attn(const float* __restrict__ biasC, bf16_t* __restrict__ qkv) {
  __shared__ __align__(16) bf16_t Ps[4 * 64 * 72];   // 36864 B
  const int tid = threadIdx.x, wid = tid >> 6, lane = tid & 63;
  const int p = blockIdx.x * 4 + wid;                 // 12288 problems
  const int b = p / 768, rem = p - b * 768;
  const int head = rem >> 6, w = rem & 63;
  const int wy = w >> 3, wx = w & 7;
  const int cls = ((wy == 7) ? 1 : 0) | ((wx == 7) ? 2 : 0);
  const int lc = lane & 15, quad = lane >> 4;
  const size_t wbase = ((size_t)b * 3136 + (size_t)wy * 7 * 56 + (size_t)wx * 7) * 1152
                       + head * 32;

  auto rowoff = [&](int m) -> size_t {
    int ty = m / 7, tx = m - ty * 7;
    return wbase + (size_t)(ty * 56 + tx) * 1152;
  };

  bf16x8 qf[4], kf[4];
#pragma unroll
  for (int t = 0; t < 4; ++t) {
    int m = t * 16 + lc; if (m > 48) m = 48;
    const bf16_t* r = qkv + rowoff(m);
    qf[t] = *(const bf16x8*)(r + quad * 8);
    kf[t] = *(const bf16x8*)(r + 384 + quad * 8);
  }

  bf16x8 vf[2][2];
#pragma unroll
  for (int kc = 0; kc < 2; ++kc)
#pragma unroll
    for (int u = 0; u < 8; ++u) {
      int n = kc * 32 + quad * 8 + u; if (n > 48) n = 48;
      const bf16_t* r = qkv + rowoff(n) + 768 + lc;
      vf[kc][0][u] = r[0];
      vf[kc][1][u] = r[16];
    }

  f32x4 acc[4][4];
  const float* bp = biasC + cls * 4096 + lane * 4;
#pragma unroll
  for (int mt = 0; mt < 4; ++mt)
#pragma unroll
    for (int nt = 0; nt < 4; ++nt)
      acc[mt][nt] = *(const f32x4*)(bp + (mt * 4 + nt) * 256);
  __builtin_amdgcn_s_setprio(1);
#pragma unroll
  for (int mt = 0; mt < 4; ++mt)
#pragma unroll
    for (int nt = 0; nt < 4; ++nt)
      acc[mt][nt] = __builtin_amdgcn_mfma_f32_16x16x32_bf16(qf[mt], kf[nt], acc[mt][nt], 0, 0, 0);
  __builtin_amdgcn_s_setprio(0);

  float l[4][4];
#pragma unroll
  for (int mt = 0; mt < 4; ++mt)
#pragma unroll
    for (int reg = 0; reg < 4; ++reg) {
      float mx = fmaxf(fmaxf(acc[mt][0][reg], acc[mt][1][reg]),
                       fmaxf(acc[mt][2][reg], acc[mt][3][reg]));
      mx = rowmax16(mx);
      float s = 0.f;
#pragma unroll
      for (int nt = 0; nt < 4; ++nt) {
        float pe = __expf((acc[mt][nt][reg] - mx) * SCALE);
        acc[mt][nt][reg] = pe;
        s += pe;
      }
      l[mt][reg] = rowsum16(s);
    }

  bf16_t* P = Ps + wid * (64 * 72);
#pragma unroll
  for (int mt = 0; mt < 4; ++mt)
#pragma unroll
    for (int nt = 0; nt < 4; ++nt)
#pragma unroll
      for (int reg = 0; reg < 4; ++reg)
        P[(mt * 16 + quad * 4 + reg) * 72 + nt * 16 + lc] = (bf16_t)acc[mt][nt][reg];

  f32x4 oacc[4][2] = {};
#pragma unroll
  for (int mt = 0; mt < 4; ++mt) {
    bf16x8 pf0 = *(const bf16x8*)(P + (mt * 16 + lc) * 72 + quad * 8);
    bf16x8 pf1 = *(const bf16x8*)(P + (mt * 16 + lc) * 72 + 32 + quad * 8);
    __builtin_amdgcn_s_setprio(1);
#pragma unroll
    for (int dt = 0; dt < 2; ++dt) {
      oacc[mt][dt] = __builtin_amdgcn_mfma_f32_16x16x32_bf16(pf0, vf[0][dt], oacc[mt][dt], 0, 0, 0);
      oacc[mt][dt] = __builtin_amdgcn_mfma_f32_16x16x32_bf16(pf1, vf[1][dt], oacc[mt][dt], 0, 0, 0);
    }
    __builtin_amdgcn_s_setprio(0);
  }

#pragma unroll
  for (int mt = 0; mt < 4; ++mt)
#pragma unroll
    for (int reg = 0; reg < 4; ++reg) {
      int m = mt * 16 + quad * 4 + reg;
      if (m < 49) {
        float rl = __builtin_amdgcn_rcpf(l[mt][reg]);
        bf16_t* r = qkv + rowoff(m);
        r[lc]      = (bf16_t)(oacc[mt][0][reg] * rl);
        r[16 + lc] = (bf16_t)(oacc[mt][1][reg] * rl);
      }
    }
}

// ---------------------------------------------------------------------------
extern "C" void kernel_launch(void* const* d_in, const int* in_sizes, int n_in,
                              void* d_out, int out_size, void* d_ws, size_t ws_size,
                              hipStream_t stream) {
  const float* x      = (const float*)d_in[0];
  const float* w_qkv  = (const float*)d_in[1];
  const float* pos    = (const float*)d_in[2];
  const float* w_out  = (const float*)d_in[3];
  const float* b_out  = (const float*)d_in[4];
  const float* w_post = (const float*)d_in[5];
  const float* b_post = (const float*)d_in[6];
  float* out = (float*)d_out;

  const size_t SZ_QKV  = (size_t)M_TOT * 1152 * 2;   // 115.6 MB
  const size_t SZ_WT   = (size_t)1152 * 384 * 2;
  const size_t SZ_WC   = (size_t)384 * 384 * 2;
  const size_t SZ_BC   = 384 * 4;
  const size_t SZ_BIAS = (size_t)4 * 16 * 64 * 4 * 4;  // 64 KB
  const size_t NEEDED  = SZ_QKV + SZ_WT + SZ_WC + SZ_BC + SZ_BIAS;

  if (ws_size < NEEDED) {
    k_zero<<<(out_size + 255) / 256, 256, 0, stream>>>(out, out_size);
    return;
  }

  char* ws = (char*)d_ws;
  bf16_t* qkv   = (bf16_t*)ws;
  bf16_t* wT    = (bf16_t*)(ws + SZ_QKV);
  bf16_t* wcT   = (bf16_t*)(ws + SZ_QKV + SZ_WT);
  float*  bc    = (float*)(ws + SZ_QKV + SZ_WT + SZ_WC);
  float*  biasC = (float*)(ws + SZ_QKV + SZ_WT + SZ_WC + SZ_BC);
  bf16_t* xb    = (bf16_t*)d_out;   // d_out as scratch; dead before final GEMM

  k_transpose<<<108, 256, 0, stream>>>(w_qkv, wT);
  k_comb<<<dim3(6, 6), 256, 0, stream>>>(w_out, b_out, w_post, b_post, wcT, bc);
  k_bias<<<64, 256, 0, stream>>>(pos, biasC);
  k_convroll<<<(M_TOT * 48 + 255) / 256, 256, 0, stream>>>(x, xb);
  // qkv = xb @ w_qkv^T-laid-out   [50176 x 1152] bf16
  k_gemm_qkv<<<dim3(9, 392), 256, 0, stream>>>(xb, wT, qkv, nullptr, 1152, DIMK, DIMK);
  // attention in place (q slot)
  k_attn<<<3072, 256, 0, stream>>>(biasC, qkv);
  // out = roll^{-1}( attn @ wcomb + bcomb )   [50176 x 384] fp32
  k_gemm_out<<<dim3(3, 392), 256, 0, stream>>>(qkv, wcT, out, bc, 384, DIMK, 1152);
}